// Round 3
// baseline (260.368 us; speedup 1.0000x reference)
//
#include <hip/hip_runtime.h>

// Problem constants
#define NB   2
#define ND   16
#define NH   64
#define DHW  65536       // D*H*W
#define HW   4096        // H*W
#define CDHW 16777216    // C*D*H*W

// LDS strides (elements)
#define QK_LD 40         // Qh/Ql/Kh/Kl row stride (ushort): 32 + 8 pad
#define A_LD  72         // Ah/Al row stride (ushort)
#define VB_LD 72         // V round-trip buffer row stride (ushort)

// LDS regions (bytes), total 47104 -> 3 blocks/CU
// R1 [0,18432):      Xth[64][64] swz (8192) + Xtl[64][64] swz (8192)  ->  Ah[64][72], Al[64][72]
// R2 [18432,36864):  Kh/Kl[64][40] (10240)  ->  Vb 4 waves x 4608 B
// R3 [36864,47104):  Qh[64][40], Ql[64][40]
#define OFF_XTH 0
#define OFF_XTL 8192
#define OFF_AH  0
#define OFF_AL  9216
#define OFF_R2  18432
#define OFF_KH  18432
#define OFF_KL  23552
#define OFF_QH  36864
#define OFF_QL  41984
#define SMEM_BYTES 47104

typedef __attribute__((ext_vector_type(4))) float f32x4;
typedef __attribute__((ext_vector_type(8))) short bf16x8;
typedef unsigned short ushort_t;

#define MFMA16(a, b, c) __builtin_amdgcn_mfma_f32_16x16x32_bf16((a), (b), (c), 0, 0, 0)

// ws layout (ushort elements)
#define WS_WQH 0
#define WS_WQL 8192
#define WS_WKH 16384
#define WS_WKL 24576
#define WS_WVH 32768
#define WS_WVL 98304
#define WS_NEED_BYTES 327680

__device__ __forceinline__ void split_val(float f, short& h, short& l) {
  unsigned int u = __builtin_bit_cast(unsigned int, f);
  h = (short)(unsigned short)(u >> 16);
  float fh = __builtin_bit_cast(float, u & 0xffff0000u);
  float r = f - fh;
  l = (short)(unsigned short)(__builtin_bit_cast(unsigned int, r) >> 16);
}

__device__ __forceinline__ void load_split8(const float* __restrict__ p, bf16x8& h8, bf16x8& l8) {
  float4 a = *(const float4*)p;
  float4 b = *(const float4*)(p + 4);
  float f[8] = {a.x, a.y, a.z, a.w, b.x, b.y, b.z, b.w};
#pragma unroll
  for (int j = 0; j < 8; ++j) {
    short hh, ll;
    split_val(f[j], hh, ll);
    h8[j] = hh; l8[j] = ll;
  }
}

// ---------------- weight pre-split kernel ----------------
__global__ void prep_w(const float* __restrict__ Wq, const float* __restrict__ Wk,
                       const float* __restrict__ Wv, ushort_t* __restrict__ ws) {
  int idx = blockIdx.x * 256 + threadIdx.x;
  const float* src; int off; ushort_t *H, *L;
  if (idx < 8192)       { src = Wq; off = idx;         H = ws + WS_WQH; L = ws + WS_WQL; }
  else if (idx < 16384) { src = Wk; off = idx - 8192;  H = ws + WS_WKH; L = ws + WS_WKL; }
  else if (idx < 81920) { src = Wv; off = idx - 16384; H = ws + WS_WVH; L = ws + WS_WVL; }
  else return;
  short h, l;
  split_val(src[off], h, l);
  H[off] = (ushort_t)h;
  L[off] = (ushort_t)l;
}

// ---------------- main kernel ----------------
template<bool PW>
__global__ __launch_bounds__(256, 3) void xattn(
    const float* __restrict__ x1, const float* __restrict__ x2,
    const float* __restrict__ Wq, const float* __restrict__ bq,
    const float* __restrict__ Wk, const float* __restrict__ bk,
    const float* __restrict__ Wv, const float* __restrict__ bv,
    const ushort_t* __restrict__ wsp, float* __restrict__ out)
{
  __shared__ char smem[SMEM_BYTES];
  ushort_t* Xth = (ushort_t*)(smem + OFF_XTH);   // [64 rows x][128 B], XOR-swizzled
  ushort_t* Xtl = (ushort_t*)(smem + OFF_XTL);
  ushort_t* Kh  = (ushort_t*)(smem + OFF_KH);
  ushort_t* Kl  = (ushort_t*)(smem + OFF_KL);
  ushort_t* Vb  = (ushort_t*)(smem + OFF_R2);
  ushort_t* Ah  = (ushort_t*)(smem + OFF_AH);
  ushort_t* Al  = (ushort_t*)(smem + OFF_AL);
  ushort_t* Qh  = (ushort_t*)(smem + OFF_QH);
  ushort_t* Ql  = (ushort_t*)(smem + OFF_QL);

  const int tid  = threadIdx.x;
  const int lane = tid & 63;
  const int wv   = tid >> 6;
  const int l15  = lane & 15;
  const int g    = lane >> 4;

  const int grp = blockIdx.x;
  const int b   = grp >> 10;
  const int rem = grp & 1023;
  const int d   = rem >> 6;
  const int h   = rem & 63;
  const size_t base = (size_t)b * CDHW + (size_t)d * HW + (size_t)h * 64;

  const ushort_t* WqH = wsp + WS_WQH;
  const ushort_t* WqL = wsp + WS_WQL;
  const ushort_t* WkH = wsp + WS_WKH;
  const ushort_t* WkL = wsp + WS_WKL;
  const ushort_t* WvH = wsp + WS_WVH;
  const ushort_t* WvL = wsp + WS_WVL;

  const float* x1p = x1 + base;
  const float* x2p = x2 + base;

  // prefetch regs: 16 channels (wave's quarter) x this lane's x-position
  float pf[16];
  auto issue_pf = [&](const float* __restrict__ src) {
#pragma unroll
    for (int j = 0; j < 16; ++j)
      pf[j] = src[(size_t)(16 * wv + j) * DHW + lane];
  };
  // convert pf -> split bf16 frags (pre-barrier VALU work)
  bf16x8 sh0, sl0, sh1, sl1;
  auto cvt = [&]() {
#pragma unroll
    for (int j = 0; j < 8; ++j) {
      short hh, ll;
      split_val(pf[j], hh, ll);
      sh0[j] = hh; sl0[j] = ll;
    }
#pragma unroll
    for (int j = 0; j < 8; ++j) {
      short hh, ll;
      split_val(pf[8 + j], hh, ll);
      sh1[j] = hh; sl1[j] = ll;
    }
  };
  // write frags to swizzled Xth/Xtl (row = lane = x, cols = wave's 16 channels)
  auto write_x = [&]() {
    int c0 = 16 * wv;
    int bo0 = lane * 128 + (((c0)     * 2) ^ ((lane & 7) << 4));
    int bo1 = lane * 128 + (((c0 + 8) * 2) ^ ((lane & 7) << 4));
    *(bf16x8*)((char*)Xth + bo0) = sh0;
    *(bf16x8*)((char*)Xtl + bo0) = sl0;
    *(bf16x8*)((char*)Xth + bo1) = sh1;
    *(bf16x8*)((char*)Xtl + bo1) = sl1;
  };
  // swizzled fragment read
  auto ldsx = [&](const ushort_t* B, int row, int ko) -> bf16x8 {
    return *(const bf16x8*)((const char*)B + row * 128 + (((ko) * 2) ^ ((row & 7) << 4)));
  };

  // ===== loop 1: stream x1 c-tiles, accumulate Q^T =====
  {
    f32x4 qacc[2];
#pragma unroll
    for (int mt = 0; mt < 2; ++mt) {
      int r0 = mt * 16 + 4 * g;
      qacc[mt] = (f32x4){bq[r0], bq[r0 + 1], bq[r0 + 2], bq[r0 + 3]};
    }
    issue_pf(x1p);
    for (int t = 0; t < 4; ++t) {
      cvt();
      __syncthreads();            // previous tile's readers done
      write_x();
      issue_pf(t < 3 ? x1p + (size_t)(t + 1) * 64 * DHW : x2p);  // cross-loop prefetch at t==3
      __syncthreads();            // frags visible
#pragma unroll
      for (int ks = 0; ks < 2; ++ks) {
        const int ko = ks * 32 + 8 * g;
        const int kg = t * 64 + ko;
        bf16x8 bh = ldsx(Xth, 16 * wv + l15, ko);
        bf16x8 bl = ldsx(Xtl, 16 * wv + l15, ko);
#pragma unroll
        for (int mt = 0; mt < 2; ++mt) {
          bf16x8 wh, wl;
          if constexpr (PW) {
            wh = *(const bf16x8*)&WqH[(size_t)(mt * 16 + l15) * 256 + kg];
            wl = *(const bf16x8*)&WqL[(size_t)(mt * 16 + l15) * 256 + kg];
          } else {
            load_split8(Wq + (size_t)(mt * 16 + l15) * 256 + kg, wh, wl);
          }
          qacc[mt] = MFMA16(wh, bh, qacc[mt]);
          qacc[mt] = MFMA16(wh, bl, qacc[mt]);
          qacc[mt] = MFMA16(wl, bh, qacc[mt]);
        }
      }
    }
    // write Q split to R3
    const int x = 16 * wv + l15;
#pragma unroll
    for (int mt = 0; mt < 2; ++mt)
#pragma unroll
      for (int r = 0; r < 4; ++r) {
        short hh, ll;
        split_val(qacc[mt][r], hh, ll);
        Qh[x * QK_LD + mt * 16 + 4 * g + r] = (ushort_t)hh;
        Ql[x * QK_LD + mt * 16 + 4 * g + r] = (ushort_t)ll;
      }
  }

  // ===== loop 2: stream x2 c-tiles, accumulate K^T + V =====
  f32x4 vacc[4][4];
  {
    f32x4 kacc[2];
#pragma unroll
    for (int mt = 0; mt < 2; ++mt) {
      int r0 = mt * 16 + 4 * g;
      kacc[mt] = (f32x4){bk[r0], bk[r0 + 1], bk[r0 + 2], bk[r0 + 3]};
    }
#pragma unroll
    for (int mt = 0; mt < 4; ++mt) {
      int r0 = 64 * wv + mt * 16 + 4 * g;
      f32x4 bb = (f32x4){bv[r0], bv[r0 + 1], bv[r0 + 2], bv[r0 + 3]};
#pragma unroll
      for (int nt = 0; nt < 4; ++nt) vacc[mt][nt] = bb;
    }
    for (int t = 0; t < 4; ++t) {
      cvt();
      __syncthreads();
      write_x();
      if (t < 3) issue_pf(x2p + (size_t)(t + 1) * 64 * DHW);
      __syncthreads();
#pragma unroll
      for (int ks = 0; ks < 2; ++ks) {
        const int ko = ks * 32 + 8 * g;
        const int kg = t * 64 + ko;
        bf16x8 xh[4], xl[4];
#pragma unroll
        for (int nt = 0; nt < 4; ++nt) {
          xh[nt] = ldsx(Xth, nt * 16 + l15, ko);
          xl[nt] = ldsx(Xtl, nt * 16 + l15, ko);
        }
        // K (B-frag re-loaded explicitly: no runtime-indexed reg array)
        {
          bf16x8 bh = ldsx(Xth, 16 * wv + l15, ko);
          bf16x8 bl = ldsx(Xtl, 16 * wv + l15, ko);
#pragma unroll
          for (int mt = 0; mt < 2; ++mt) {
            bf16x8 wh, wl;
            if constexpr (PW) {
              wh = *(const bf16x8*)&WkH[(size_t)(mt * 16 + l15) * 256 + kg];
              wl = *(const bf16x8*)&WkL[(size_t)(mt * 16 + l15) * 256 + kg];
            } else {
              load_split8(Wk + (size_t)(mt * 16 + l15) * 256 + kg, wh, wl);
            }
            kacc[mt] = MFMA16(wh, bh, kacc[mt]);
            kacc[mt] = MFMA16(wh, bl, kacc[mt]);
            kacc[mt] = MFMA16(wl, bh, kacc[mt]);
          }
        }
        // V
#pragma unroll
        for (int mt = 0; mt < 4; ++mt) {
          bf16x8 wh, wl;
          if constexpr (PW) {
            wh = *(const bf16x8*)&WvH[(size_t)(64 * wv + mt * 16 + l15) * 256 + kg];
            wl = *(const bf16x8*)&WvL[(size_t)(64 * wv + mt * 16 + l15) * 256 + kg];
          } else {
            load_split8(Wv + (size_t)(64 * wv + mt * 16 + l15) * 256 + kg, wh, wl);
          }
#pragma unroll
          for (int nt = 0; nt < 4; ++nt) {
            vacc[mt][nt] = MFMA16(wh, xh[nt], vacc[mt][nt]);
            vacc[mt][nt] = MFMA16(wh, xl[nt], vacc[mt][nt]);
            vacc[mt][nt] = MFMA16(wl, xh[nt], vacc[mt][nt]);
          }
        }
      }
    }
    // write K split to R2
    const int y = 16 * wv + l15;
#pragma unroll
    for (int mt = 0; mt < 2; ++mt)
#pragma unroll
      for (int r = 0; r < 4; ++r) {
        short hh, ll;
        split_val(kacc[mt][r], hh, ll);
        Kh[y * QK_LD + mt * 16 + 4 * g + r] = (ushort_t)hh;
        Kl[y * QK_LD + mt * 16 + 4 * g + r] = (ushort_t)ll;
      }
  }
  __syncthreads();

  // ===== phase 3: A = Q^T K (64x64), split-stored into R1 (Xth/Xtl dead) =====
  {
    const int y = 16 * wv + l15;
    bf16x8 kh = *(const bf16x8*)&Kh[y * QK_LD + 8 * g];
    bf16x8 kl = *(const bf16x8*)&Kl[y * QK_LD + 8 * g];
    f32x4 acc[4];
#pragma unroll
    for (int mt = 0; mt < 4; ++mt) acc[mt] = (f32x4){0.f, 0.f, 0.f, 0.f};
#pragma unroll
    for (int mt = 0; mt < 4; ++mt) {
      bf16x8 qh = *(const bf16x8*)&Qh[(mt * 16 + l15) * QK_LD + 8 * g];
      bf16x8 ql = *(const bf16x8*)&Ql[(mt * 16 + l15) * QK_LD + 8 * g];
      acc[mt] = MFMA16(qh, kh, acc[mt]);
      acc[mt] = MFMA16(qh, kl, acc[mt]);
      acc[mt] = MFMA16(ql, kh, acc[mt]);
    }
#pragma unroll
    for (int mt = 0; mt < 4; ++mt)
#pragma unroll
      for (int r = 0; r < 4; ++r) {
        short hh, ll;
        split_val(acc[mt][r], hh, ll);
        Ah[(mt * 16 + 4 * g + r) * A_LD + y] = (ushort_t)hh;
        Al[(mt * 16 + 4 * g + r) * A_LD + y] = (ushort_t)ll;
      }
  }
  __syncthreads();

  // ===== phase 4: Out = V * A^T, per 16-row c-tile via per-wave LDS round-trip =====
  {
    ushort_t* Vh = Vb + wv * 2304;   // [16][72] hi
    ushort_t* Vl = Vh + 1152;        // [16][72] lo
    const int cb = 64 * wv;
#pragma unroll
    for (int mt = 0; mt < 4; ++mt) {
#pragma unroll
      for (int nt = 0; nt < 4; ++nt)
#pragma unroll
        for (int r = 0; r < 4; ++r) {
          short hh, ll;
          split_val(vacc[mt][nt][r], hh, ll);
          Vh[(4 * g + r) * VB_LD + nt * 16 + l15] = (ushort_t)hh;
          Vl[(4 * g + r) * VB_LD + nt * 16 + l15] = (ushort_t)ll;
        }
      f32x4 oacc[4];
#pragma unroll
      for (int nt = 0; nt < 4; ++nt) oacc[nt] = (f32x4){0.f, 0.f, 0.f, 0.f};
#pragma unroll
      for (int ys = 0; ys < 2; ++ys) {
        const int yo = ys * 32 + 8 * g;
        bf16x8 vh8 = *(const bf16x8*)&Vh[l15 * VB_LD + yo];
        bf16x8 vl8 = *(const bf16x8*)&Vl[l15 * VB_LD + yo];
#pragma unroll
        for (int nt = 0; nt < 4; ++nt) {
          bf16x8 ah8 = *(const bf16x8*)&Ah[(nt * 16 + l15) * A_LD + yo];
          bf16x8 al8 = *(const bf16x8*)&Al[(nt * 16 + l15) * A_LD + yo];
          oacc[nt] = MFMA16(vh8, ah8, oacc[nt]);
          oacc[nt] = MFMA16(vh8, al8, oacc[nt]);
          oacc[nt] = MFMA16(vl8, ah8, oacc[nt]);
        }
      }
#pragma unroll
      for (int nt = 0; nt < 4; ++nt)
#pragma unroll
        for (int r = 0; r < 4; ++r)
          out[base + (size_t)(cb + mt * 16 + 4 * g + r) * DHW + nt * 16 + l15] = oacc[nt][r];
    }
  }
}

extern "C" void kernel_launch(void* const* d_in, const int* in_sizes, int n_in,
                              void* d_out, int out_size, void* d_ws, size_t ws_size,
                              hipStream_t stream)
{
  const float* x1 = (const float*)d_in[0];
  const float* x2 = (const float*)d_in[1];
  const float* Wq = (const float*)d_in[2];
  const float* bq = (const float*)d_in[3];
  const float* Wk = (const float*)d_in[4];
  const float* bk = (const float*)d_in[5];
  const float* Wv = (const float*)d_in[6];
  const float* bv = (const float*)d_in[7];
  float* out = (float*)d_out;

  const bool pw = (ws_size >= (size_t)WS_NEED_BYTES) && (d_ws != nullptr);
  if (pw) {
    ushort_t* ws = (ushort_t*)d_ws;
    hipLaunchKernelGGL(prep_w, dim3(320), dim3(256), 0, stream, Wq, Wk, Wv, ws);
    hipLaunchKernelGGL(xattn<true>, dim3(NB * ND * NH), dim3(256), 0, stream,
                       x1, x2, Wq, bq, Wk, bk, Wv, bv, ws, out);
  } else {
    hipLaunchKernelGGL(xattn<false>, dim3(NB * ND * NH), dim3(256), 0, stream,
                       x1, x2, Wq, bq, Wk, bk, Wv, bv, (const ushort_t*)nullptr, out);
  }
}